// Round 1
// baseline (42.417 us; speedup 1.0000x reference)
//
#include <hip/hip_runtime.h>

#define NTHREADS 256
#define SPT 2  // samples per thread

__device__ __forceinline__ float fast_sigmoid(float x) {
    return __builtin_amdgcn_rcpf(1.0f + __expf(-x));
}

// LDS weight layout, per branch k (stride 48 floats):
//   [0..19]  W1[k][h][i] at h*5+i
//   [20..23] b1[k][h]
//   [24..39] W2[k][g][h] at g*4+h
//   [40..43] b2[k][g]
//   [44..47] folded final weight fw[k][h]  (fc3 [+fc4] collapsed)
// [288..291] folded output biases fb[0..3]
__global__ __launch_bounds__(NTHREADS, 4)
void mlp6_fused_kernel(const float* __restrict__ xl,
                       const float* __restrict__ yl,
                       const float* __restrict__ xr,
                       const float* __restrict__ W1, const float* __restrict__ b1,
                       const float* __restrict__ W2, const float* __restrict__ b2,
                       const float* __restrict__ W3_2, const float* __restrict__ b3_2,
                       const float* __restrict__ W3_1, const float* __restrict__ b3_1,
                       const float* __restrict__ W4, const float* __restrict__ b4,
                       float* __restrict__ out, int B)
{
    __shared__ __align__(16) float w[296];
    const int tid = threadIdx.x;

    // ---- stage + fold weights into LDS ----
    for (int t = tid; t < 292; t += NTHREADS) {
        float v;
        if (t < 264) {
            int k = t / 44, r = t % 44;
            if (r < 20)      v = W1[k*20 + r];
            else if (r < 24) v = b1[k*4 + (r-20)];
            else if (r < 40) v = W2[k*16 + (r-24)];
            else             v = b2[k*4 + (r-40)];
            w[k*48 + r] = v;
        } else if (t < 288) {
            int q = t - 264, k = q >> 2, h = q & 3;
            // W3_2 flat [4][2][4]: j*8+o*4+h ; rows j: 0->br0, 1->br1, 2->br4, 3->br5
            // W4 flat [2][1][4] ; W3_1 flat [2][1][4]
            if (k == 0)      v = W4[0]*W3_2[h]     + W4[1]*W3_2[4+h];
            else if (k == 1) v = W4[4]*W3_2[8+h]   + W4[5]*W3_2[12+h];
            else if (k == 2) v = W3_1[h];
            else if (k == 3) v = W3_1[4+h];
            else if (k == 4) v = W4[2]*W3_2[16+h]  + W4[3]*W3_2[20+h];
            else             v = W4[6]*W3_2[24+h]  + W4[7]*W3_2[28+h];
            w[k*48 + 44 + h] = v;
        } else {
            int j = t - 288;
            // b3_2 flat [4][2]: j*2+o
            if (j == 0)      v = b3_1[0];
            else if (j == 1) v = b3_1[1];
            else if (j == 2) v = W4[0]*b3_2[0] + W4[1]*b3_2[1] + W4[2]*b3_2[4] + W4[3]*b3_2[5] + b4[0];
            else             v = W4[4]*b3_2[2] + W4[5]*b3_2[3] + W4[6]*b3_2[6] + W4[7]*b3_2[7] + b4[1];
            w[288 + j] = v;
        }
    }
    __syncthreads();

    const float fb0 = w[288], fb1 = w[289], fb2 = w[290], fb3 = w[291];

    long long base = (long long)blockIdx.x * (NTHREADS * SPT) + tid;
    long long idx[SPT];
    #pragma unroll
    for (int s = 0; s < SPT; s++) {
        long long i = base + (long long)s * NTHREADS;
        idx[s] = (i < B) ? i : (long long)(B - 1);  // clamped dup-writes are identical
    }

    // inputs: xs[s][0..4]=xl, [5..9]=yl, [10..14]=xr
    float xs[SPT][15];
    #pragma unroll
    for (int s = 0; s < SPT; s++) {
        long long p = idx[s] * 5;
        #pragma unroll
        for (int j = 0; j < 5; j++) {
            xs[s][j]      = xl[p + j];
            xs[s][5 + j]  = yl[p + j];
            xs[s][10 + j] = xr[p + j];
        }
    }

    float o[SPT][4];
    #pragma unroll
    for (int s = 0; s < SPT; s++) { o[s][0]=fb0; o[s][1]=fb1; o[s][2]=fb2; o[s][3]=fb3; }

    // branch -> input slice offset in xs; branch -> output slot
    // X = stack([xl, yl, xr, yl, xl, yl]); out slots: br2->o0, br3->o1, {br0,br4}->o2, {br1,br5}->o3
    constexpr int xoff[6] = {0, 5, 10, 5, 0, 5};
    constexpr int oidx[6] = {2, 3, 0, 1, 2, 3};

    #pragma unroll
    for (int k = 0; k < 6; k++) {
        // register-stage this branch's 48 weights via 12x ds_read_b128,
        // amortized over SPT samples
        float wk[48];
        const float4* w4p = (const float4*)&w[k*48];
        #pragma unroll
        for (int q = 0; q < 12; q++) {
            float4 t4 = w4p[q];
            wk[q*4+0]=t4.x; wk[q*4+1]=t4.y; wk[q*4+2]=t4.z; wk[q*4+3]=t4.w;
        }
        #pragma unroll
        for (int s = 0; s < SPT; s++) {
            float h1[4];
            #pragma unroll
            for (int h = 0; h < 4; h++) {
                float a = wk[20+h];
                #pragma unroll
                for (int i = 0; i < 5; i++) a = fmaf(xs[s][xoff[k]+i], wk[h*5+i], a);
                h1[h] = fast_sigmoid(a);
            }
            float h2[4];
            #pragma unroll
            for (int g = 0; g < 4; g++) {
                float a = wk[40+g];
                #pragma unroll
                for (int h = 0; h < 4; h++) a = fmaf(h1[h], wk[24+g*4+h], a);
                h2[g] = fast_sigmoid(a);
            }
            float c = 0.0f;
            #pragma unroll
            for (int h = 0; h < 4; h++) c = fmaf(h2[h], wk[44+h], c);
            o[s][oidx[k]] += c;
        }
    }

    #pragma unroll
    for (int s = 0; s < SPT; s++) {
        float4 r; r.x = o[s][0]; r.y = o[s][1]; r.z = o[s][2]; r.w = o[s][3];
        ((float4*)out)[idx[s]] = r;
    }
}

extern "C" void kernel_launch(void* const* d_in, const int* in_sizes, int n_in,
                              void* d_out, int out_size, void* d_ws, size_t ws_size,
                              hipStream_t stream) {
    const float* xl   = (const float*)d_in[0];
    const float* yl   = (const float*)d_in[1];
    const float* xr   = (const float*)d_in[2];
    // d_in[3] = yr — unused by the reference forward
    const float* W1   = (const float*)d_in[4];
    const float* b1   = (const float*)d_in[5];
    const float* W2   = (const float*)d_in[6];
    const float* b2   = (const float*)d_in[7];
    const float* W3_2 = (const float*)d_in[8];
    const float* b3_2 = (const float*)d_in[9];
    const float* W3_1 = (const float*)d_in[10];
    const float* b3_1 = (const float*)d_in[11];
    const float* W4   = (const float*)d_in[12];
    const float* b4   = (const float*)d_in[13];
    float* out = (float*)d_out;

    int B = in_sizes[0] / 5;
    int blocks = (B + NTHREADS * SPT - 1) / (NTHREADS * SPT);
    mlp6_fused_kernel<<<blocks, NTHREADS, 0, stream>>>(
        xl, yl, xr, W1, b1, W2, b2, W3_2, b3_2, W3_1, b3_1, W4, b4, out, B);
}